// Round 7
// baseline (263.690 us; speedup 1.0000x reference)
//
#include <hip/hip_runtime.h>
#include <hip/hip_bf16.h>

typedef float f32x4 __attribute__((ext_vector_type(4)));
typedef short bf16x8 __attribute__((ext_vector_type(8)));

#define MFMA16 __builtin_amdgcn_mfma_f32_16x16x32_bf16

static constexpr int KDIM = 1700;
static constexpr int NKT  = 54;         // k-tiles of 32 (tile 53 ragged: 4 valid)
static constexpr float BETA = 0.9f;
static constexpr float THRESH = 1.0f;

// DIAGNOSTIC ROUND: kernels repeat their (idempotent) work REP times so each
// dispatch exceeds the 62us fillBuffer floor and shows up in rocprof top-5.
static constexpr int REP_G = 4;
static constexpr int REP_R = 24;

// fp32 -> bf16 hi + bf16 lo (residual), via HW cvt
__device__ __forceinline__ void split_bf(float f, short& hi, short& lo) {
    __hip_bfloat16 h = __float2bfloat16(f);
    float r = f - __bfloat162float(h);          // exact in fp32
    __hip_bfloat16 l = __float2bfloat16(r);
    hi = (short)__builtin_bit_cast(unsigned short, h);
    lo = (short)__builtin_bit_cast(unsigned short, l);
}

__device__ __forceinline__ void split8(f32x4 a, f32x4 b, bf16x8& hi, bf16x8& lo) {
    #pragma unroll
    for (int i = 0; i < 4; ++i) { short h, l; split_bf(a[i], h, l); hi[i] = h; lo[i] = l; }
    #pragma unroll
    for (int i = 0; i < 4; ++i) { short h, l; split_bf(b[i], h, l); hi[4 + i] = h; lo[4 + i] = l; }
}

// W1 [64][1700] f32 -> two bf16 planes in MFMA-B-fragment order:
// WT[((kt*4 + nt)*64 + lane)*8 + i] = W1[nt*16 + (lane&15)][kt*32 + (lane>>4)*8 + i]
__global__ void w1_relayout(const float* __restrict__ W1,
                            short* __restrict__ WTh, short* __restrict__ WTl) {
    const int g    = blockIdx.x * 256 + threadIdx.x;   // 0 .. 54*256-1
    const int kt   = g >> 8;
    const int nt   = (g >> 6) & 3;
    const int lane = g & 63;
    const int n    = nt * 16 + (lane & 15);
    const int kb   = kt * 32 + (lane >> 4) * 8;
    bf16x8 vh, vl;
    #pragma unroll
    for (int i = 0; i < 8; ++i) {
        const int k = kb + i;
        const float v = (k < KDIM) ? W1[n * KDIM + k] : 0.f;
        short h, l; split_bf(v, h, l);
        vh[i] = h; vl[i] = l;
    }
    *(bf16x8*)(WTh + (size_t)g * 8) = vh;
    *(bf16x8*)(WTl + (size_t)g * 8) = vl;
}

// ---------------- kernel A: cur1 = x @ W1^T + b1 (r3 structure, x REP_G) ----
__global__ __launch_bounds__(256, 2) void gemm1(
    const float* __restrict__ x,
    const short* __restrict__ WTh, const short* __restrict__ WTl,
    const float* __restrict__ b1, float* __restrict__ cur1)
{
    __shared__ float red[4][32][68];
    const int tid = threadIdx.x;
    const int wid = tid >> 6;
    const int lane = tid & 63;
    const int l15 = lane & 15;
    const int g4  = lane >> 4;
    const int kg  = g4 * 8;
    const int rowBase = blockIdx.x * 32;

    const int t0  = wid * 13 + (wid < 2 ? wid : 2);    // {0,14,28,41}
    const int t1  = t0 + 14 - (wid >> 1);              // {14,28,41,54}
    const int t1e = (wid == 3) ? 53 : t1;              // tile 53 handled apart

    const float* xr0 = x + (size_t)(rowBase + l15) * KDIM + kg;
    const float* xr1 = xr0 + (size_t)16 * KDIM;

    for (int rep = 0; rep < REP_G; ++rep) {
        f32x4 acc[2][4] = {};
        f32x4 p00 = *(const f32x4*)(xr0 + t0 * 32);
        f32x4 p01 = *(const f32x4*)(xr0 + t0 * 32 + 4);
        f32x4 p10 = *(const f32x4*)(xr1 + t0 * 32);
        f32x4 p11 = *(const f32x4*)(xr1 + t0 * 32 + 4);

        for (int t = t0; t < t1e; ++t) {
            f32x4 a00 = p00, a01 = p01, a10 = p10, a11 = p11;
            if (t + 1 < t1e) {
                p00 = *(const f32x4*)(xr0 + (t + 1) * 32);
                p01 = *(const f32x4*)(xr0 + (t + 1) * 32 + 4);
                p10 = *(const f32x4*)(xr1 + (t + 1) * 32);
                p11 = *(const f32x4*)(xr1 + (t + 1) * 32 + 4);
            }
            const short* wb = WTh + (size_t)t * 2048 + lane * 8;
            const short* wl = WTl + (size_t)t * 2048 + lane * 8;
            bf16x8 bh[4], bl[4];
            #pragma unroll
            for (int nt = 0; nt < 4; ++nt) {
                bh[nt] = *(const bf16x8*)(wb + nt * 512);
                bl[nt] = *(const bf16x8*)(wl + nt * 512);
            }
            bf16x8 ah0, al0, ah1, al1;
            split8(a00, a01, ah0, al0);
            split8(a10, a11, ah1, al1);
            #pragma unroll
            for (int nt = 0; nt < 4; ++nt) {
                acc[0][nt] = MFMA16(ah0, bh[nt], acc[0][nt], 0, 0, 0);
                acc[0][nt] = MFMA16(al0, bh[nt], acc[0][nt], 0, 0, 0);
                acc[0][nt] = MFMA16(ah0, bl[nt], acc[0][nt], 0, 0, 0);
                acc[1][nt] = MFMA16(ah1, bh[nt], acc[1][nt], 0, 0, 0);
                acc[1][nt] = MFMA16(al1, bh[nt], acc[1][nt], 0, 0, 0);
                acc[1][nt] = MFMA16(ah1, bl[nt], acc[1][nt], 0, 0, 0);
            }
        }
        if (wid == 3) {                       // ragged k-tile 53 (k 1696..1699)
            f32x4 a00 = {0,0,0,0}, a01 = {0,0,0,0}, a10 = {0,0,0,0}, a11 = {0,0,0,0};
            if (g4 == 0) {
                a00 = *(const f32x4*)(xr0 + 53 * 32);
                a10 = *(const f32x4*)(xr1 + 53 * 32);
            }
            const short* wb = WTh + (size_t)53 * 2048 + lane * 8;
            const short* wl = WTl + (size_t)53 * 2048 + lane * 8;
            bf16x8 bh[4], bl[4];
            #pragma unroll
            for (int nt = 0; nt < 4; ++nt) {
                bh[nt] = *(const bf16x8*)(wb + nt * 512);
                bl[nt] = *(const bf16x8*)(wl + nt * 512);
            }
            bf16x8 ah0, al0, ah1, al1;
            split8(a00, a01, ah0, al0);
            split8(a10, a11, ah1, al1);
            #pragma unroll
            for (int nt = 0; nt < 4; ++nt) {
                acc[0][nt] = MFMA16(ah0, bh[nt], acc[0][nt], 0, 0, 0);
                acc[0][nt] = MFMA16(al0, bh[nt], acc[0][nt], 0, 0, 0);
                acc[0][nt] = MFMA16(ah0, bl[nt], acc[0][nt], 0, 0, 0);
                acc[1][nt] = MFMA16(ah1, bh[nt], acc[1][nt], 0, 0, 0);
                acc[1][nt] = MFMA16(al1, bh[nt], acc[1][nt], 0, 0, 0);
                acc[1][nt] = MFMA16(ah1, bl[nt], acc[1][nt], 0, 0, 0);
            }
        }

        // partials -> LDS (C-layout: row = mt*16 + g4*4 + j, col = nt*16 + l15)
        #pragma unroll
        for (int mt = 0; mt < 2; ++mt)
            #pragma unroll
            for (int nt = 0; nt < 4; ++nt)
                #pragma unroll
                for (int j = 0; j < 4; ++j)
                    red[wid][mt * 16 + g4 * 4 + j][nt * 16 + l15] = acc[mt][nt][j];
        __syncthreads();

        // reduce 4 k-partials + b1, write cur1 (row-major [B][64])
        {
            const int rr  = tid >> 3;             // 0..31
            const int seg = tid & 7;              // 8-float column segment
            f32x4 s0 = {0,0,0,0}, s1 = {0,0,0,0};
            #pragma unroll
            for (int p = 0; p < 4; ++p) {
                s0 += *(const f32x4*)&red[p][rr][seg * 8];
                s1 += *(const f32x4*)&red[p][rr][seg * 8 + 4];
            }
            s0 += *(const f32x4*)(b1 + seg * 8);
            s1 += *(const f32x4*)(b1 + seg * 8 + 4);
            float* cp = cur1 + (size_t)(rowBase + rr) * 64 + seg * 8;
            *(f32x4*)cp = s0;
            *(f32x4*)(cp + 4) = s1;
        }
        __syncthreads();                          // red reads done before next rep
    }
}

// ---------------- kernel B: LIF recurrence + projection (r3, x REP_R) -------
__global__ __launch_bounds__(256, 2) void recur(
    const float* __restrict__ cur1, const float* __restrict__ W2,
    const float* __restrict__ b2, const float* __restrict__ W3,
    const float* __restrict__ b3, const int* __restrict__ nsp,
    float* __restrict__ out)
{
    const int tid = threadIdx.x;
    const int wid = tid >> 6;
    const int lane = tid & 63;
    const int l15 = lane & 15;
    const int g4  = lane >> 4;
    const int kg  = g4 * 8;
    const int row = blockIdx.x * 64 + wid * 16 + l15;

    float c1[2][8];
    #pragma unroll
    for (int kt = 0; kt < 2; ++kt) {
        f32x4 u0 = *(const f32x4*)(cur1 + (size_t)row * 64 + kt * 32 + kg);
        f32x4 u1 = *(const f32x4*)(cur1 + (size_t)row * 64 + kt * 32 + kg + 4);
        #pragma unroll
        for (int i = 0; i < 4; ++i) { c1[kt][i] = u0[i]; c1[kt][4 + i] = u1[i]; }
    }

    bf16x8 W2hf[2][2], W2lf[2][2];
    #pragma unroll
    for (int rt = 0; rt < 2; ++rt)
        #pragma unroll
        for (int kt = 0; kt < 2; ++kt) {
            const float* wp = W2 + (rt * 16 + l15) * 64 + kt * 32 + kg;
            split8(*(const f32x4*)wp, *(const f32x4*)(wp + 4), W2hf[rt][kt], W2lf[rt][kt]);
        }

    float b2v[2][4], w3a[2][4], w3b[2][4];
    #pragma unroll
    for (int nt = 0; nt < 2; ++nt)
        #pragma unroll
        for (int j = 0; j < 4; ++j) {
            const int o = nt * 16 + g4 * 4 + j;
            b2v[nt][j] = b2[o];
            w3a[nt][j] = W3[o];
            w3b[nt][j] = W3[32 + o];
        }

    const int ns = nsp[0];
    for (int rep = 0; rep < REP_R; ++rep) {
        float m1[2][8] = {};
        float m2[2][4] = {};
        for (int s = 0; s < ns; ++s) {
            bf16x8 mh[2], ml[2];
            #pragma unroll
            for (int kt = 0; kt < 2; ++kt)
                #pragma unroll
                for (int i = 0; i < 8; ++i) {
                    float m = m1[kt][i];
                    float rr = (m > THRESH) ? THRESH : 0.f;
                    m = __builtin_fmaf(BETA, m, c1[kt][i] - rr);
                    m1[kt][i] = m;
                    short h, l; split_bf(m, h, l);
                    mh[kt][i] = h; ml[kt][i] = l;
                }
            f32x4 a2[2][2] = {};
            #pragma unroll
            for (int rt = 0; rt < 2; ++rt)
                #pragma unroll
                for (int kt = 0; kt < 2; ++kt) {
                    a2[rt][kt] = MFMA16(W2hf[rt][kt], mh[kt], a2[rt][kt], 0, 0, 0);
                    a2[rt][kt] = MFMA16(W2lf[rt][kt], mh[kt], a2[rt][kt], 0, 0, 0);
                    a2[rt][kt] = MFMA16(W2hf[rt][kt], ml[kt], a2[rt][kt], 0, 0, 0);
                }
            #pragma unroll
            for (int nt = 0; nt < 2; ++nt) {
                f32x4 c2 = a2[nt][0] + a2[nt][1];
                #pragma unroll
                for (int j = 0; j < 4; ++j) {
                    float m = m2[nt][j];
                    float rr = (m > THRESH) ? THRESH : 0.f;
                    m2[nt][j] = __builtin_fmaf(BETA, m, c2[j] + b2v[nt][j] - rr);
                }
            }
        }

        float p0 = 0.f, p1 = 0.f;
        #pragma unroll
        for (int nt = 0; nt < 2; ++nt)
            #pragma unroll
            for (int j = 0; j < 4; ++j) {
                p0 = __builtin_fmaf(m2[nt][j], w3a[nt][j], p0);
                p1 = __builtin_fmaf(m2[nt][j], w3b[nt][j], p1);
            }
        p0 += __shfl_xor(p0, 16); p0 += __shfl_xor(p0, 32);
        p1 += __shfl_xor(p1, 16); p1 += __shfl_xor(p1, 32);
        if (lane < 16) {
            out[(size_t)row * 2 + 0] = p0 + b3[0];
            out[(size_t)row * 2 + 1] = p1 + b3[1];
        }
    }
}

extern "C" void kernel_launch(void* const* d_in, const int* in_sizes, int n_in,
                              void* d_out, int out_size, void* d_ws, size_t ws_size,
                              hipStream_t stream) {
    const float* x  = (const float*)d_in[0];
    const float* W1 = (const float*)d_in[1];
    const float* b1 = (const float*)d_in[2];
    const float* W2 = (const float*)d_in[3];
    const float* b2 = (const float*)d_in[4];
    const float* W3 = (const float*)d_in[5];
    const float* b3 = (const float*)d_in[6];
    const int*   ns = (const int*)d_in[7];
    float* o = (float*)d_out;

    const int B = in_sizes[0] / KDIM;              // 16384
    float* cur1 = (float*)d_ws;                    // [B][64] f32 = 4 MB
    short* WTh  = (short*)((char*)d_ws + (size_t)B * 64 * 4);
    short* WTl  = WTh + (size_t)NKT * 2048;        // each plane 54*2048 shorts

    w1_relayout<<<NKT, 256, 0, stream>>>(W1, WTh, WTl);
    gemm1<<<B / 32, 256, 0, stream>>>(x, WTh, WTl, b1, cur1);
    recur<<<B / 64, 256, 0, stream>>>(cur1, W2, b2, W3, b3, ns, o);
}

// Round 8
// 44.074 us; speedup vs baseline: 5.9829x; 5.9829x over previous
//
#include <hip/hip_runtime.h>
#include <hip/hip_bf16.h>

typedef float f32x4 __attribute__((ext_vector_type(4)));
typedef short bf16x8 __attribute__((ext_vector_type(8)));

#define MFMA16 __builtin_amdgcn_mfma_f32_16x16x32_bf16

static constexpr int KDIM = 1700;
static constexpr int NKT  = 54;         // k-tiles of 32 (tile 53 ragged: 4 valid)
static constexpr float BETA = 0.9f;
static constexpr float THRESH = 1.0f;

// fp32 -> bf16 hi + bf16 lo (residual), via HW cvt
__device__ __forceinline__ void split_bf(float f, short& hi, short& lo) {
    __hip_bfloat16 h = __float2bfloat16(f);
    float r = f - __bfloat162float(h);          // exact in fp32
    __hip_bfloat16 l = __float2bfloat16(r);
    hi = (short)__builtin_bit_cast(unsigned short, h);
    lo = (short)__builtin_bit_cast(unsigned short, l);
}

__device__ __forceinline__ void split8(f32x4 a, f32x4 b, bf16x8& hi, bf16x8& lo) {
    #pragma unroll
    for (int i = 0; i < 4; ++i) { short h, l; split_bf(a[i], h, l); hi[i] = h; lo[i] = l; }
    #pragma unroll
    for (int i = 0; i < 4; ++i) { short h, l; split_bf(b[i], h, l); hi[4 + i] = h; lo[4 + i] = l; }
}

// W1 [64][1700] f32 -> two bf16 planes in MFMA-B-fragment order:
// WT[((kt*4 + nt)*64 + lane)*8 + i] = W1[nt*16 + (lane&15)][kt*32 + (lane>>4)*8 + i]
__global__ void w1_relayout(const float* __restrict__ W1,
                            short* __restrict__ WTh, short* __restrict__ WTl) {
    const int g    = blockIdx.x * 256 + threadIdx.x;   // 0 .. 54*256-1
    const int kt   = g >> 8;
    const int nt   = (g >> 6) & 3;
    const int lane = g & 63;
    const int n    = nt * 16 + (lane & 15);
    const int kb   = kt * 32 + (lane >> 4) * 8;
    bf16x8 vh, vl;
    #pragma unroll
    for (int i = 0; i < 8; ++i) {
        const int k = kb + i;
        const float v = (k < KDIM) ? W1[n * KDIM + k] : 0.f;
        short h, l; split_bf(v, h, l);
        vh[i] = h; vl[i] = l;
    }
    *(bf16x8*)(WTh + (size_t)g * 8) = vh;
    *(bf16x8*)(WTl + (size_t)g * 8) = vl;
}

// ---------------- fused kernel: cur1 GEMM (in LDS) + LIF recurrence ----------
// Block = 256 thr = 4 waves, 32 rows/block. Phase 1: r3's K-split-4 GEMM,
// partials reduced in LDS (cur1 never touches global). Phase 2: waves 0-1
// run the 20-step recurrence for 16 rows each; waves 2-3 exit.
__global__ __launch_bounds__(256, 2) void snn_fused(
    const float* __restrict__ x,
    const short* __restrict__ WTh, const short* __restrict__ WTl,
    const float* __restrict__ b1, const float* __restrict__ W2,
    const float* __restrict__ b2, const float* __restrict__ W3,
    const float* __restrict__ b3, const int* __restrict__ nsp,
    float* __restrict__ out)
{
    __shared__ float red[4][32][68];
    const int tid = threadIdx.x;
    const int wid = tid >> 6;
    const int lane = tid & 63;
    const int l15 = lane & 15;
    const int g4  = lane >> 4;
    const int kg  = g4 * 8;
    const int rowBase = blockIdx.x * 32;

    // ---------------- phase 1: cur1 partial GEMM (split-bf16 emulated fp32) --
    {
        const int t0  = wid * 13 + (wid < 2 ? wid : 2);    // {0,14,28,41}
        const int t1  = t0 + 14 - (wid >> 1);              // {14,28,41,54}
        const int t1e = (wid == 3) ? 53 : t1;              // tile 53 handled apart

        const float* xr0 = x + (size_t)(rowBase + l15) * KDIM + kg;
        const float* xr1 = xr0 + (size_t)16 * KDIM;

        f32x4 acc[2][4] = {};
        f32x4 p00 = *(const f32x4*)(xr0 + t0 * 32);
        f32x4 p01 = *(const f32x4*)(xr0 + t0 * 32 + 4);
        f32x4 p10 = *(const f32x4*)(xr1 + t0 * 32);
        f32x4 p11 = *(const f32x4*)(xr1 + t0 * 32 + 4);

        for (int t = t0; t < t1e; ++t) {
            f32x4 a00 = p00, a01 = p01, a10 = p10, a11 = p11;
            if (t + 1 < t1e) {
                p00 = *(const f32x4*)(xr0 + (t + 1) * 32);
                p01 = *(const f32x4*)(xr0 + (t + 1) * 32 + 4);
                p10 = *(const f32x4*)(xr1 + (t + 1) * 32);
                p11 = *(const f32x4*)(xr1 + (t + 1) * 32 + 4);
            }
            const short* wb = WTh + (size_t)t * 2048 + lane * 8;
            const short* wl = WTl + (size_t)t * 2048 + lane * 8;
            bf16x8 bh[4], bl[4];
            #pragma unroll
            for (int nt = 0; nt < 4; ++nt) {
                bh[nt] = *(const bf16x8*)(wb + nt * 512);
                bl[nt] = *(const bf16x8*)(wl + nt * 512);
            }
            bf16x8 ah0, al0, ah1, al1;
            split8(a00, a01, ah0, al0);
            split8(a10, a11, ah1, al1);
            #pragma unroll
            for (int nt = 0; nt < 4; ++nt) {
                acc[0][nt] = MFMA16(ah0, bh[nt], acc[0][nt], 0, 0, 0);
                acc[0][nt] = MFMA16(al0, bh[nt], acc[0][nt], 0, 0, 0);
                acc[0][nt] = MFMA16(ah0, bl[nt], acc[0][nt], 0, 0, 0);
                acc[1][nt] = MFMA16(ah1, bh[nt], acc[1][nt], 0, 0, 0);
                acc[1][nt] = MFMA16(al1, bh[nt], acc[1][nt], 0, 0, 0);
                acc[1][nt] = MFMA16(ah1, bl[nt], acc[1][nt], 0, 0, 0);
            }
        }
        if (wid == 3) {                       // ragged k-tile 53 (k 1696..1699)
            f32x4 a00 = {0,0,0,0}, a01 = {0,0,0,0}, a10 = {0,0,0,0}, a11 = {0,0,0,0};
            if (g4 == 0) {
                a00 = *(const f32x4*)(xr0 + 53 * 32);
                a10 = *(const f32x4*)(xr1 + 53 * 32);
            }
            const short* wb = WTh + (size_t)53 * 2048 + lane * 8;
            const short* wl = WTl + (size_t)53 * 2048 + lane * 8;
            bf16x8 bh[4], bl[4];
            #pragma unroll
            for (int nt = 0; nt < 4; ++nt) {
                bh[nt] = *(const bf16x8*)(wb + nt * 512);
                bl[nt] = *(const bf16x8*)(wl + nt * 512);
            }
            bf16x8 ah0, al0, ah1, al1;
            split8(a00, a01, ah0, al0);
            split8(a10, a11, ah1, al1);
            #pragma unroll
            for (int nt = 0; nt < 4; ++nt) {
                acc[0][nt] = MFMA16(ah0, bh[nt], acc[0][nt], 0, 0, 0);
                acc[0][nt] = MFMA16(al0, bh[nt], acc[0][nt], 0, 0, 0);
                acc[0][nt] = MFMA16(ah0, bl[nt], acc[0][nt], 0, 0, 0);
                acc[1][nt] = MFMA16(ah1, bh[nt], acc[1][nt], 0, 0, 0);
                acc[1][nt] = MFMA16(al1, bh[nt], acc[1][nt], 0, 0, 0);
                acc[1][nt] = MFMA16(ah1, bl[nt], acc[1][nt], 0, 0, 0);
            }
        }

        // partials -> LDS (C-layout: row = mt*16 + g4*4 + j, col = nt*16 + l15)
        #pragma unroll
        for (int mt = 0; mt < 2; ++mt)
            #pragma unroll
            for (int nt = 0; nt < 4; ++nt)
                #pragma unroll
                for (int j = 0; j < 4; ++j)
                    red[wid][mt * 16 + g4 * 4 + j][nt * 16 + l15] = acc[mt][nt][j];
    }
    __syncthreads();

    // reduce 4 k-partials + b1 into red[0] (each thread's (rr,seg) slots are
    // disjoint: read-all-4 then write red[0] is race-free)
    {
        const int rr  = tid >> 3;             // 0..31
        const int seg = tid & 7;              // 8-float column segment
        f32x4 s0 = *(const f32x4*)(b1 + seg * 8);
        f32x4 s1 = *(const f32x4*)(b1 + seg * 8 + 4);
        #pragma unroll
        for (int p = 0; p < 4; ++p) {
            s0 += *(const f32x4*)&red[p][rr][seg * 8];
            s1 += *(const f32x4*)&red[p][rr][seg * 8 + 4];
        }
        *(f32x4*)&red[0][rr][seg * 8]     = s0;
        *(f32x4*)&red[0][rr][seg * 8 + 4] = s1;
    }
    __syncthreads();
    if (wid >= 2) return;                     // waves 2,3 done (no barriers below)

    // ---------------- phase 2: 20-step LIF recurrence, all in registers ------
    const int lrow = wid * 16 + l15;          // row within block

    // lane holds cur1[lrow][kt*32 + kg + i]; precompute c1 - 1 for reset-select
    float c1[2][8], c1m1[2][8];
    #pragma unroll
    for (int kt = 0; kt < 2; ++kt) {
        f32x4 u0 = *(const f32x4*)&red[0][lrow][kt * 32 + kg];
        f32x4 u1 = *(const f32x4*)&red[0][lrow][kt * 32 + kg + 4];
        #pragma unroll
        for (int i = 0; i < 4; ++i) {
            c1[kt][i] = u0[i];     c1[kt][4 + i] = u1[i];
            c1m1[kt][i] = u0[i] - THRESH; c1m1[kt][4 + i] = u1[i] - THRESH;
        }
    }

    // W2 as MFMA A-operand: lane holds W2[rt*16+l15][kt*32+kg+i], split hi/lo
    bf16x8 W2hf[2][2], W2lf[2][2];
    #pragma unroll
    for (int rt = 0; rt < 2; ++rt)
        #pragma unroll
        for (int kt = 0; kt < 2; ++kt) {
            const float* wp = W2 + (rt * 16 + l15) * 64 + kt * 32 + kg;
            split8(*(const f32x4*)wp, *(const f32x4*)(wp + 4), W2hf[rt][kt], W2lf[rt][kt]);
        }

    // per-lane D-layout constants: out-channel o = nt*16 + g4*4 + j
    float b2v[2][4], b2m1[2][4], w3a[2][4], w3b[2][4];
    #pragma unroll
    for (int nt = 0; nt < 2; ++nt)
        #pragma unroll
        for (int j = 0; j < 4; ++j) {
            const int o = nt * 16 + g4 * 4 + j;
            b2v[nt][j]  = b2[o];
            b2m1[nt][j] = b2[o] - THRESH;
            w3a[nt][j] = W3[o];
            w3b[nt][j] = W3[32 + o];
        }

    float m1[2][8] = {};
    float m2[2][4] = {};
    const int ns = nsp[0];
    for (int s = 0; s < ns; ++s) {
        bf16x8 mh[2], ml[2];
        #pragma unroll
        for (int kt = 0; kt < 2; ++kt)
            #pragma unroll
            for (int i = 0; i < 8; ++i) {
                float m = m1[kt][i];
                m = __builtin_fmaf(BETA, m, (m > THRESH) ? c1m1[kt][i] : c1[kt][i]);
                m1[kt][i] = m;
                short h, l; split_bf(m, h, l);
                mh[kt][i] = h; ml[kt][i] = l;
            }
        f32x4 a2[2][2] = {};
        #pragma unroll
        for (int rt = 0; rt < 2; ++rt)
            #pragma unroll
            for (int kt = 0; kt < 2; ++kt) {
                a2[rt][kt] = MFMA16(W2hf[rt][kt], mh[kt], a2[rt][kt], 0, 0, 0);
                a2[rt][kt] = MFMA16(W2lf[rt][kt], mh[kt], a2[rt][kt], 0, 0, 0);
                a2[rt][kt] = MFMA16(W2hf[rt][kt], ml[kt], a2[rt][kt], 0, 0, 0);
            }
        #pragma unroll
        for (int nt = 0; nt < 2; ++nt) {
            f32x4 c2 = a2[nt][0] + a2[nt][1];
            #pragma unroll
            for (int j = 0; j < 4; ++j) {
                float m = m2[nt][j];
                m2[nt][j] = __builtin_fmaf(
                    BETA, m, c2[j] + ((m > THRESH) ? b2m1[nt][j] : b2v[nt][j]));
            }
        }
    }

    // out = mem2 @ W3^T + b3 (reduce over the 4 lane-groups)
    float p0 = 0.f, p1 = 0.f;
    #pragma unroll
    for (int nt = 0; nt < 2; ++nt)
        #pragma unroll
        for (int j = 0; j < 4; ++j) {
            p0 = __builtin_fmaf(m2[nt][j], w3a[nt][j], p0);
            p1 = __builtin_fmaf(m2[nt][j], w3b[nt][j], p1);
        }
    p0 += __shfl_xor(p0, 16); p0 += __shfl_xor(p0, 32);
    p1 += __shfl_xor(p1, 16); p1 += __shfl_xor(p1, 32);
    if (lane < 16) {
        const size_t row = rowBase + lrow;
        out[row * 2 + 0] = p0 + b3[0];
        out[row * 2 + 1] = p1 + b3[1];
    }
}

extern "C" void kernel_launch(void* const* d_in, const int* in_sizes, int n_in,
                              void* d_out, int out_size, void* d_ws, size_t ws_size,
                              hipStream_t stream) {
    const float* x  = (const float*)d_in[0];
    const float* W1 = (const float*)d_in[1];
    const float* b1 = (const float*)d_in[2];
    const float* W2 = (const float*)d_in[3];
    const float* b2 = (const float*)d_in[4];
    const float* W3 = (const float*)d_in[5];
    const float* b3 = (const float*)d_in[6];
    const int*   ns = (const int*)d_in[7];
    float* o = (float*)d_out;

    const int B = in_sizes[0] / KDIM;              // 16384
    short* WTh  = (short*)d_ws;                    // [54][2048] bf16 hi
    short* WTl  = WTh + (size_t)NKT * 2048;        // [54][2048] bf16 lo

    w1_relayout<<<NKT, 256, 0, stream>>>(W1, WTh, WTl);
    snn_fused<<<B / 32, 256, 0, stream>>>(x, WTh, WTl, b1, W2, b2, W3, b3, ns, o);
}